// Round 6
// baseline (191.630 us; speedup 1.0000x reference)
//
#include <hip/hip_runtime.h>
#include <hip/hip_bf16.h>

typedef __attribute__((ext_vector_type(8))) short bf16x8;    // 8 bf16 = 4 VGPR
typedef __attribute__((ext_vector_type(16))) float f32x16;   // 32x32 accumulator
typedef unsigned int u32;

#define MOD_SCALE 0.04419417382415922f     // 1/sqrt(512)
#define CONV_SCALE 0.014731391274719742f   // 1/sqrt(512*9)

__device__ __forceinline__ unsigned short f2bf(float f) {
  union { float f; u32 u; } v; v.f = f;
  u32 r = v.u + 0x7fffu + ((v.u >> 16) & 1u);   // RNE
  return (unsigned short)(r >> 16);
}

__device__ __forceinline__ void gload_lds16(const void* g, void* l) {
  __builtin_amdgcn_global_load_lds(
      (const __attribute__((address_space(1))) u32*)g,
      (__attribute__((address_space(3))) u32*)l, 16, 0, 0);
}

// ---- k_prep: blocks 0..1023 = weight prep (LDS-coalesced), 1024..1039 = style GEMV.
// wb layout: [tap 9][icb 32][oc 512][ic 16] bf16.
__global__ void k_prep(const float* __restrict__ wsrc, ushort* __restrict__ wb,
                       float* __restrict__ wsq, float* __restrict__ zerobuf,
                       const float* __restrict__ style, const float* __restrict__ mw,
                       const float* __restrict__ mb, float* __restrict__ s) {
  __shared__ float wtile[2304];
  const int t = threadIdx.x;
  if (blockIdx.x < 1024) {
    // coalesced load of this block's 256 (oc,ic) x 9 taps = 2304 floats
    const float4* s4 = (const float4*)(wsrc + (size_t)blockIdx.x * 2304);
    float4* w4 = (float4*)wtile;
    w4[t] = s4[t];
    w4[t + 256] = s4[t + 256];
    if (t < 64) w4[t + 512] = s4[t + 512];
    __syncthreads();
    int idx = blockIdx.x * 256 + t;   // oc*512+ic
    int oc = idx >> 9, ic = idx & 511;
    int icb = ic >> 4, icr = ic & 15;
    if (blockIdx.x == 0 && t < 16) zerobuf[t] = 0.f;
    float sq = 0.f;
    #pragma unroll
    for (int tap = 0; tap < 9; ++tap) {
      float v = wtile[t * 9 + tap];
      sq += v * v;
      wb[((tap * 32 + icb) * 512 + oc) * 16 + icr] = f2bf(v);
    }
    wsq[idx] = sq;
  } else {
    int idx = (blockIdx.x - 1024) * 256 + t;   // b*512+ic
    int b = idx >> 9, ic = idx & 511;
    const float4* wr = (const float4*)(mw + ic * 512);
    const float4* sr = (const float4*)(style + b * 512);
    float acc = 0.f;
    #pragma unroll 4
    for (int k = 0; k < 128; ++k) {
      float4 a = wr[k], c = sr[k];
      acc += a.x * c.x + a.y * c.y + a.z * c.z + a.w * c.w;
    }
    s[idx] = acc * MOD_SCALE + mb[ic];
  }
}

// ---- k_xform: xsb[b][y][icb 32][x 64][ic 16] = bf16(x[b][ic][y][x] * s[b][ic])
__global__ void k_xform(const float* __restrict__ x, const float* __restrict__ s,
                        ushort* __restrict__ xsb) {
  const int y = blockIdx.x, b = blockIdx.y;
  const int t = threadIdx.x;
  const int px = t & 63, icq = t >> 6;
  #pragma unroll
  for (int i = 0; i < 8; ++i) {
    int icb = i * 4 + icq;
    union { ushort u[16]; uint4 v[2]; } pk;
    #pragma unroll
    for (int j = 0; j < 16; ++j) {
      int ic = icb * 16 + j;
      float v = x[(b * 512 + ic) * 4096 + y * 64 + px] * s[b * 512 + ic];
      pk.u[j] = f2bf(v);
    }
    ushort* dst = xsb + ((size_t)((b * 64 + y) * 32 + icb) * 64 + px) * 16;
    *(uint4*)dst = pk.v[0];
    *(uint4*)(dst + 8) = pk.v[1];
  }
}

// ---- k_conv: implicit-GEMM conv, mfma_f32_32x32x16_bf16, counted-vmcnt pipeline.
// Block 64oc x 8rows x 64px, 4 waves; wave = 2 rows, acc[2][2][2] f32x16.
// Per K-step: A[9tap][64oc][16ic] 18432B + B[10rows][64px][16ic] rows of 2080B
// (2048 staged + 32B persistent zero-line for the x-halo). Uniform 10
// global_load_lds per thread per step; raw s_barrier + s_waitcnt vmcnt(10)
// keeps next-next-step loads in flight across barriers (T3/T4). setprio on MFMA (T5).
#define ABYTES 18432
#define BROW   2080
#define BUFB   (ABYTES + 10 * BROW)     // 39232
#define TRASHO (2 * BUFB)               // 1024 B trash for dummy loads
#define REDOFF (2 * BUFB + 1024)
#define DSSOFF (2 * BUFB + 2048)
#define SMEMSZ (2 * BUFB + 2048 + 256)  // 80768 <= 81920 -> 2 blocks/CU

__global__ __launch_bounds__(256, 2) void k_conv(
    const ushort* __restrict__ wb, const ushort* __restrict__ xsb,
    const float* __restrict__ wsq, const float* __restrict__ s,
    const float* __restrict__ zerobuf, float* __restrict__ out) {
  const int yb = blockIdx.x, ocb = blockIdx.y, b = blockIdx.z;
  const int t = threadIdx.x;
  const int wv = t >> 6, l = t & 63;
  const int lc = l & 31, lh = l >> 5;
  const int y0 = yb * 8, oc0 = ocb * 64;

  extern __shared__ char smem[];
  float* red = (float*)(smem + REDOFF);
  float* dss = (float*)(smem + DSSOFF);

  f32x16 acc[2][2][2];
  #pragma unroll
  for (int rr = 0; rr < 2; ++rr)
    #pragma unroll
    for (int ocf = 0; ocf < 2; ++ocf)
      #pragma unroll
      for (int pxf = 0; pxf < 2; ++pxf)
        #pragma unroll
        for (int k = 0; k < 16; ++k)
          acc[rr][ocf][pxf][k] = 0.f;

  // ---- per-lane staging source tables (10 groups; group = one gload per thread)
  // slots: [0,1152) = A chunks, [1152,2432) = B chunks (10 rows x 128), rest dummy.
  const char* gsrc[10];
  int gstr[10];
  #pragma unroll
  for (int i = 0; i < 10; ++i) {
    int s0 = i * 256 + t;
    if (s0 < 1152) {                       // A: tap, oc_l, half
      int tap = s0 >> 7, cc = s0 & 127, oc_l = cc >> 1, h = cc & 1;
      gsrc[i] = (const char*)wb + (size_t)tap * 524288 + (size_t)(oc0 + oc_l) * 32 + h * 16;
      gstr[i] = 16384;
    } else if (s0 < 2432) {                // B: row, px, half
      int c = s0 - 1152, r = c >> 7, cc = c & 127, px = cc >> 1, h = cc & 1;
      int yy = y0 - 1 + r;
      bool ok = (unsigned)yy < 64u;
      gsrc[i] = ok ? (const char*)xsb + ((size_t)(b * 64 + yy) * 2048 + px) * 32 + h * 16
                   : (const char*)zerobuf;
      gstr[i] = ok ? 2048 : 0;
    } else {                               // dummy
      gsrc[i] = (const char*)zerobuf;
      gstr[i] = 0;
    }
  }

  // fragment-read offsets (linear layout, no swizzle)
  int apo[2];
  apo[0] = (lc * 2 + lh) * 16;
  apo[1] = apo[0] + 1024;
  int boff[3][2];
  #pragma unroll
  for (int dx = 0; dx < 3; ++dx)
    #pragma unroll
    for (int pxf = 0; pxf < 2; ++pxf) {
      int px = pxf * 32 + dx - 1 + lc;
      boff[dx][pxf] = ((unsigned)px < 64u) ? px * 32 + lh * 16 : 2048 + lh * 16;
    }

  auto STAGE = [&](int bo, int icb) {
    #pragma unroll
    for (int i = 0; i < 10; ++i) {
      char* dst;
      if (i <= 3)      dst = smem + bo + (i * 256 + wv * 64) * 16;
      else if (i == 4) dst = (wv < 2) ? smem + bo + (1024 + wv * 64) * 16
                                      : smem + bo + ABYTES + (wv - 2) * 1024;
      else if (i <= 8) dst = smem + bo + ABYTES + ((i - 5) * 2 + 1 + (wv >> 1)) * BROW + (wv & 1) * 1024;
      else             dst = (wv < 2) ? smem + bo + ABYTES + 9 * BROW + wv * 1024
                                      : smem + TRASHO;
      gload_lds16(gsrc[i] + (size_t)(icb * gstr[i]), dst);
    }
  };

  auto COMPUTE = [&](int bo) {
    const char* Ab = smem + bo;
    const char* Bb = smem + bo + ABYTES;
    #pragma unroll
    for (int dx = 0; dx < 3; ++dx) {
      bf16x8 bfr[4][2];
      #pragma unroll
      for (int j = 0; j < 4; ++j)
        #pragma unroll
        for (int pxf = 0; pxf < 2; ++pxf)
          bfr[j][pxf] = *(const bf16x8*)(Bb + (wv * 2 + j) * BROW + boff[dx][pxf]);
      bf16x8 af[3][2];
      #pragma unroll
      for (int dy = 0; dy < 3; ++dy)
        #pragma unroll
        for (int ocf = 0; ocf < 2; ++ocf)
          af[dy][ocf] = *(const bf16x8*)(Ab + (dy * 3 + dx) * 2048 + apo[ocf]);
      __builtin_amdgcn_s_setprio(1);
      #pragma unroll
      for (int dy = 0; dy < 3; ++dy)
        #pragma unroll
        for (int rr = 0; rr < 2; ++rr)
          #pragma unroll
          for (int ocf = 0; ocf < 2; ++ocf)
            #pragma unroll
            for (int pxf = 0; pxf < 2; ++pxf)
              acc[rr][ocf][pxf] = __builtin_amdgcn_mfma_f32_32x32x16_bf16(
                  af[dy][ocf], bfr[rr + dy][pxf], acc[rr][ocf][pxf], 0, 0, 0);
      __builtin_amdgcn_s_setprio(0);
    }
  };

  // ---- prologue: zero-lines, demod partial sums, first two stages
  if (t < 40) {        // 2 bufs x 10 rows x 32B zero-line at row offset 2048
    int q = t & 1, id = t >> 1;
    int bi = id / 10, r = id - bi * 10;
    *(uint4*)(smem + bi * BUFB + ABYTES + r * BROW + 2048 + q * 16) = uint4{0, 0, 0, 0};
  }
  {
    const int oc_l = t & 63, kq = t >> 6;
    const float4* wq = (const float4*)(wsq + (size_t)(oc0 + oc_l) * 512) + kq * 32;
    const float4* sp = (const float4*)(s + b * 512) + kq * 32;
    float part = 0.f;
    #pragma unroll 4
    for (int k = 0; k < 32; ++k) {
      float4 a = wq[k], c = sp[k];
      part += a.x * c.x * c.x + a.y * c.y * c.y + a.z * c.z * c.z + a.w * c.w * c.w;
    }
    red[t] = part;
  }
  STAGE(0, 0);
  STAGE(BUFB, 1);
  asm volatile("s_waitcnt lgkmcnt(0)" ::: "memory");
  asm volatile("s_barrier" ::: "memory");
  if (t < 64)
    dss[t] = CONV_SCALE * rsqrtf(
        CONV_SCALE * CONV_SCALE * (red[t] + red[t + 64] + red[t + 128] + red[t + 192]) + 1e-8f);
  asm volatile("s_waitcnt vmcnt(10) lgkmcnt(0)" ::: "memory");   // stage(0) retired, dss/zero visible
  asm volatile("s_barrier" ::: "memory");

  // ---- main loop: compute(t) | barrier | stage(t+2) | vmcnt(10) | barrier
  #pragma unroll 1
  for (int it = 0; it < 32; it += 2) {
    COMPUTE(0);
    asm volatile("s_barrier" ::: "memory");
    if (it < 30) {
      STAGE(0, it + 2);
      asm volatile("s_waitcnt vmcnt(10)" ::: "memory");
    } else {
      asm volatile("s_waitcnt vmcnt(0)" ::: "memory");
    }
    asm volatile("s_barrier" ::: "memory");

    COMPUTE(BUFB);
    asm volatile("s_barrier" ::: "memory");
    if (it + 1 < 30) {
      STAGE(BUFB, it + 3);
      asm volatile("s_waitcnt vmcnt(10)" ::: "memory");
    } else {
      asm volatile("s_waitcnt vmcnt(0)" ::: "memory");
    }
    asm volatile("s_barrier" ::: "memory");
  }

  // ---- epilogue: 32x32 D layout [m74/m101]: col(px)=lane&31, row(oc)=(reg&3)+8*(reg>>2)+4*(lane>>5)
  #pragma unroll
  for (int rr = 0; rr < 2; ++rr) {
    const int y_row = y0 + wv * 2 + rr;
    #pragma unroll
    for (int ocf = 0; ocf < 2; ++ocf) {
      #pragma unroll
      for (int pxf = 0; pxf < 2; ++pxf) {
        #pragma unroll
        for (int reg = 0; reg < 16; ++reg) {
          int oc_l = ocf * 32 + (reg & 3) + 8 * (reg >> 2) + 4 * lh;
          out[(size_t)(b * 512 + oc0 + oc_l) * 4096 + y_row * 64 + pxf * 32 + lc]
              = acc[rr][ocf][pxf][reg] * dss[oc_l];
        }
      }
    }
  }
}

extern "C" void kernel_launch(void* const* d_in, const int* in_sizes, int n_in,
                              void* d_out, int out_size, void* d_ws, size_t ws_size,
                              hipStream_t stream) {
  const float* x     = (const float*)d_in[0];  // [8,512,64,64]
  const float* style = (const float*)d_in[1];  // [8,512]
  const float* mw    = (const float*)d_in[2];  // [512,512]
  const float* mb    = (const float*)d_in[3];  // [512]
  const float* wsrc  = (const float*)d_in[4];  // [1,512,512,3,3]
  float* out = (float*)d_out;

  char* ws = (char*)d_ws;
  float*  zerobuf = (float*)(ws + 0);          //    64 B
  float*  s       = (float*)(ws + 256);        //  16 KB
  float*  wsq     = (float*)(ws + 33024);      //   1 MB
  ushort* wb      = (ushort*)(ws + 1081600);   // 4.5 MB  [9][32][512][16] bf16
  ushort* xsb     = (ushort*)(ws + 5800192);   //  32 MB  [8][64][32][64][16] bf16

  hipFuncSetAttribute(reinterpret_cast<const void*>(k_conv),
                      hipFuncAttributeMaxDynamicSharedMemorySize, SMEMSZ);

  k_prep<<<dim3(1040), dim3(256), 0, stream>>>(wsrc, wb, wsq, zerobuf, style, mw, mb, s);
  k_xform<<<dim3(64, 8), dim3(256), 0, stream>>>(x, s, xsb);
  k_conv<<<dim3(8, 8, 8), dim3(256), SMEMSZ, stream>>>(wb, xsb, wsq, s, zerobuf, out);
}